// Round 1
// baseline (9.433 us; speedup 1.0000x reference)
//
#include <hip/hip_runtime.h>

// AWPLoss reduces to a constant:
//   a_ = a  (f_prop is identity), so original_prob == enhanced_prob elementwise.
//   loss = mean(max(LAMBDA + p - p, 0)) = max(LAMBDA, 0) = LAMBDA = 0.01
// Independent of log_probs, targets, lengths, and the RNG key.

__global__ void AWPLoss_20744692040364_kernel(float* out) {
    if (threadIdx.x == 0 && blockIdx.x == 0) {
        out[0] = 0.01f;
    }
}

extern "C" void kernel_launch(void* const* d_in, const int* in_sizes, int n_in,
                              void* d_out, int out_size, void* d_ws, size_t ws_size,
                              hipStream_t stream) {
    (void)d_in; (void)in_sizes; (void)n_in; (void)out_size; (void)d_ws; (void)ws_size;
    float* out = (float*)d_out;
    AWPLoss_20744692040364_kernel<<<1, 64, 0, stream>>>(out);
}